// Round 9
// baseline (1024.165 us; speedup 1.0000x reference)
//
#include <hip/hip_runtime.h>
#include <hip/hip_bf16.h>
#include <hip/hip_cooperative_groups.h>

namespace cg = cooperative_groups;

#define N_NODES 50000
#define NUM_E   800000
#define EPS_BN  1e-5f
#define NUM_GRAPHS 64

typedef __attribute__((ext_vector_type(8))) short bf16x8;
typedef __attribute__((ext_vector_type(4))) float f32x4;
typedef unsigned short ushort_t;
typedef unsigned int uint_t;

static __device__ __forceinline__ unsigned short f2bf(float f) {
    unsigned int u = __float_as_uint(f);
    u += 0x7fffu + ((u >> 16) & 1u);   // RNE
    return (unsigned short)(u >> 16);
}
// packed f32x2 -> bf16x2 (v_cvt_pk_bf16_f32), lo in low 16 bits
static __device__ __forceinline__ uint_t pkbf(float lo, float hi) {
    __hip_bfloat162 t = __float22bfloat162_rn(make_float2(lo, hi));
    return *(uint_t*)&t;
}
static __device__ __forceinline__ float bflo(uint_t u) { return __uint_as_float(u << 16); }
static __device__ __forceinline__ float bfhi(uint_t u) { return __uint_as_float(u & 0xffff0000u); }

// ================= setup: zero + cvt(x) + prep(W) + goff + CSR build, one cooperative launch ==========
__global__ void setup_kernel(const int* __restrict__ ei, const int* __restrict__ batch,
                             const float* __restrict__ x, const float* __restrict__ W1,
                             const float* __restrict__ W2, const float* __restrict__ W3,
                             ushort_t* __restrict__ xbf, ushort_t* __restrict__ w1t,
                             ushort_t* __restrict__ w2t, ushort_t* __restrict__ w3t,
                             int* __restrict__ deg, float* __restrict__ stats3,
                             int* __restrict__ rowptr, int* __restrict__ srcs,
                             int* __restrict__ bsum, int* __restrict__ goff) {
    cg::grid_group grid = cg::this_grid();
    __shared__ int ws[4];
    int t = threadIdx.x, lane = t & 63, wv = t >> 6;
    int gtid = blockIdx.x * 256 + t;
    int gsz = gridDim.x * 256;
    const int NB = (N_NODES + 255) / 256;   // 196
    int* fill = deg + N_NODES;

    // ---- phase A: zero deg/fill/stats; cvt x->bf16; transpose W->bf16; graph offsets ----
    for (int i = gtid; i < 2 * N_NODES; i += gsz) deg[i] = 0;
    for (int i = gtid; i < 3 * 512; i += gsz) stats3[i] = 0.f;
    {
        const float4* x4 = (const float4*)x;
        uint2* xb2 = (uint2*)xbf;
        for (int i = gtid; i < N_NODES * 128 / 4; i += gsz) {
            float4 v = x4[i];
            xb2[i] = make_uint2(pkbf(v.x, v.y), pkbf(v.z, v.w));
        }
    }
    {
        const int S1 = 128 * 256, S2 = 256 * 256, S3 = 256 * 64;
        for (int i = gtid; i < S1 + S2 + S3; i += gsz) {
            if (i < S1) {
                int k = i / 256, n = i % 256;
                w1t[n * 128 + k] = f2bf(W1[i]);
            } else if (i < S1 + S2) {
                int j = i - S1; int k = j / 256, n = j % 256;
                w2t[n * 256 + k] = f2bf(W2[j]);
            } else {
                int j = i - S1 - S2; int k = j / 64, n = j % 64;
                w3t[n * 256 + k] = f2bf(W3[j]);
            }
        }
    }
    if (gtid <= NUM_GRAPHS) {   // lower_bound(batch, g)
        int g = gtid, lo = 0, hi = N_NODES;
        while (lo < hi) {
            int mid = (lo + hi) >> 1;
            if (batch[mid] < g) lo = mid + 1; else hi = mid;
        }
        goff[g] = lo;
    }
    grid.sync();

    // ---- phase B: degree histogram ----
    for (int e = gtid; e < NUM_E; e += gsz) atomicAdd(&deg[ei[NUM_E + e]], 1);
    grid.sync();

    // ---- phase C: local inclusive scan per 256-chunk ----
    if (blockIdx.x < NB) {
        int b = blockIdx.x;
        int i = b * 256 + t;
        int v = (i < N_NODES) ? deg[i] : 0;
        int incl = v;
#pragma unroll
        for (int off = 1; off < 64; off <<= 1) {
            int u = __shfl_up(incl, off, 64);
            if (lane >= off) incl += u;
        }
        if (lane == 63) ws[wv] = incl;
        __syncthreads();
        if (t == 0) {
            int s = 0;
#pragma unroll
            for (int k = 0; k < 4; ++k) { int xx = ws[k]; ws[k] = s; s += xx; }
            bsum[b] = s;
        }
        __syncthreads();
        if (i < N_NODES) rowptr[i + 1] = ws[wv] + incl;
    }
    grid.sync();

    // ---- phase D: block 0 scans the 196 block sums (exclusive) ----
    if (blockIdx.x == 0) {
        int v = (t < NB) ? bsum[t] : 0;
        int incl = v;
#pragma unroll
        for (int off = 1; off < 64; off <<= 1) {
            int u = __shfl_up(incl, off, 64);
            if (lane >= off) incl += u;
        }
        if (lane == 63) ws[wv] = incl;
        __syncthreads();
        if (t == 0) {
            int s = 0;
#pragma unroll
            for (int k = 0; k < 4; ++k) { int xx = ws[k]; ws[k] = s; s += xx; }
        }
        __syncthreads();
        if (t < NB) bsum[t] = ws[wv] + incl - v;
        if (t == 0) rowptr[0] = 0;
    }
    grid.sync();

    // ---- phase E: add block offsets ----
    for (int i = gtid; i < N_NODES; i += gsz) rowptr[i + 1] += bsum[i >> 8];
    grid.sync();

    // ---- phase F: scatter edges into CSR ----
    for (int e = gtid; e < NUM_E; e += gsz) {
        int dst = ei[NUM_E + e];
        int pos = rowptr[dst] + atomicAdd(&fill[dst], 1);
        srcs[pos] = ei[e];
    }
}

// ---------------- fused GEMM: BN-affine(A bf16)->bf16 @ Bt^T -> h(bf16) + per-head logits ----------------
template<int K, int NFULL, int BN>
__global__ __launch_bounds__(256) void gemm_fused_kernel(const ushort_t* __restrict__ A,
                                                         const ushort_t* __restrict__ Bt,
                                                         ushort_t* __restrict__ C,
                                                         const float* __restrict__ stats,
                                                         const float* __restrict__ g,
                                                         const float* __restrict__ be,
                                                         const float* __restrict__ a_src,
                                                         const float* __restrict__ a_dst,
                                                         float* __restrict__ as_,
                                                         float* __restrict__ ad_) {
    const int NT = BN / 16;
    const int NG = BN / 64;
    __shared__ __align__(16) ushort_t As[128][40];
    __shared__ __align__(16) ushort_t Bs[BN][40];
    __shared__ __align__(16) ushort_t Cs[4][32][64];
    __shared__ __align__(16) float aff_a[K], aff_b[K];
    __shared__ float asrc_s[BN], adst_s[BN];
    int tid = threadIdx.x;
    int lane = tid & 63, w = tid >> 6;
    int row0 = blockIdx.x * 128, col0 = blockIdx.y * BN;
    int m_l = lane & 15, q = lane >> 4;

    for (int c = tid; c < K; c += 256) {
        float a = 1.f, b = 0.f;
        if (stats) {
            float m = stats[c] * (1.f / N_NODES);
            float var = fmaxf(stats[256 + c] * (1.f / N_NODES) - m * m, 0.f);
            float rs = rsqrtf(var + EPS_BN) * g[c];
            a = rs; b = be[c] - m * rs;
        }
        aff_a[c] = a; aff_b[c] = b;
    }
    if (tid < BN) {
        asrc_s[tid] = a_src[col0 + tid];
        adst_s[tid] = a_dst[col0 + tid];
    }
    __syncthreads();

    f32x4 acc[2][NT];
#pragma unroll
    for (int r = 0; r < 2; ++r)
#pragma unroll
        for (int c = 0; c < NT; ++c) acc[r][c] = (f32x4){0.f, 0.f, 0.f, 0.f};

    int ar = tid >> 1, ako = (tid & 1) * 16;

    for (int k0 = 0; k0 < K; k0 += 32) {
        uint_t ow[8];
        int gr = row0 + ar;
        uint4 u0 = make_uint4(0, 0, 0, 0), u1 = make_uint4(0, 0, 0, 0);
        if (gr < N_NODES) {
            const ushort_t* ap = A + (long)gr * K + k0 + ako;
            u0 = *(const uint4*)ap;
            u1 = *(const uint4*)(ap + 8);
        }
        uint_t uu[8] = {u0.x, u0.y, u0.z, u0.w, u1.x, u1.y, u1.z, u1.w};
#pragma unroll
        for (int t = 0; t < 8; ++t) {
            int k = k0 + ako + t * 2;
            float lo = bflo(uu[t]) * aff_a[k] + aff_b[k];
            float hi = bfhi(uu[t]) * aff_a[k + 1] + aff_b[k + 1];
            ow[t] = pkbf(lo, hi);
        }
        if constexpr (BN == 128) {
            int br = tid >> 1, bko = (tid & 1) * 16;
            const ushort_t* bp = Bt + (long)(col0 + br) * K + k0 + bko;
            uint4 b0 = *(const uint4*)bp;
            uint4 b1 = *(const uint4*)(bp + 8);
            *(uint4*)&As[ar][ako] = make_uint4(ow[0], ow[1], ow[2], ow[3]);
            *(uint4*)&As[ar][ako + 8] = make_uint4(ow[4], ow[5], ow[6], ow[7]);
            *(uint4*)&Bs[br][bko] = b0;
            *(uint4*)&Bs[br][bko + 8] = b1;
        } else {
            int br = tid >> 2, bko = (tid & 3) * 8;
            uint4 bv = *(const uint4*)(Bt + (long)(col0 + br) * K + k0 + bko);
            *(uint4*)&As[ar][ako] = make_uint4(ow[0], ow[1], ow[2], ow[3]);
            *(uint4*)&As[ar][ako + 8] = make_uint4(ow[4], ow[5], ow[6], ow[7]);
            *(uint4*)&Bs[br][bko] = bv;
        }
        __syncthreads();

        bf16x8 af[2];
#pragma unroll
        for (int r = 0; r < 2; ++r)
            af[r] = *(const bf16x8*)&As[w * 32 + r * 16 + m_l][q * 8];
#pragma unroll
        for (int c = 0; c < NT; ++c) {
            bf16x8 bf = *(const bf16x8*)&Bs[c * 16 + m_l][q * 8];
#pragma unroll
            for (int r = 0; r < 2; ++r)
                acc[r][c] = __builtin_amdgcn_mfma_f32_16x16x32_bf16(af[r], bf, acc[r][c], 0, 0, 0);
        }
        __syncthreads();
    }

    const int H = NFULL / 64;
#pragma unroll
    for (int gblk = 0; gblk < NG; ++gblk) {
        int hidx = blockIdx.y * NG + gblk;
        int colg = col0 + gblk * 64;
#pragma unroll
        for (int r = 0; r < 2; ++r)
#pragma unroll
            for (int cc = 0; cc < 4; ++cc)
#pragma unroll
                for (int i = 0; i < 4; ++i)
                    Cs[w][r * 16 + q * 4 + i][cc * 16 + m_l] = f2bf(acc[r][gblk * 4 + cc][i]);
        // same-wave LDS RAW: in-order DS pipe, no barrier needed
#pragma unroll
        for (int j = 0; j < 4; ++j) {
            int flat = j * 64 + lane;
            int lr = flat >> 3, chg = flat & 7;
            int gr = row0 + w * 32 + lr;
            uint4 u = *(uint4*)&Cs[w][lr][chg * 8];
            float f0 = bflo(u.x), f1 = bfhi(u.x), f2 = bflo(u.y), f3 = bfhi(u.y);
            float f4 = bflo(u.z), f5 = bfhi(u.z), f6 = bflo(u.w), f7 = bfhi(u.w);
            int cb = gblk * 64 + chg * 8;
            float s1 = f0 * asrc_s[cb] + f1 * asrc_s[cb + 1] + f2 * asrc_s[cb + 2] + f3 * asrc_s[cb + 3]
                     + f4 * asrc_s[cb + 4] + f5 * asrc_s[cb + 5] + f6 * asrc_s[cb + 6] + f7 * asrc_s[cb + 7];
            float s2 = f0 * adst_s[cb] + f1 * adst_s[cb + 1] + f2 * adst_s[cb + 2] + f3 * adst_s[cb + 3]
                     + f4 * adst_s[cb + 4] + f5 * adst_s[cb + 5] + f6 * adst_s[cb + 6] + f7 * adst_s[cb + 7];
#pragma unroll
            for (int o = 1; o < 8; o <<= 1) {
                s1 += __shfl_xor(s1, o, 64);
                s2 += __shfl_xor(s2, o, 64);
            }
            if (gr < N_NODES) {
                *(uint4*)(C + (long)gr * NFULL + colg + chg * 8) = u;
                if ((lane & 7) == 0) {
                    as_[gr * H + hidx] = s1;
                    ad_[gr * H + hidx] = s2;
                }
            }
        }
    }
}

// ---------------- GAT aggregation H=4: quarter-wave (16 lanes) per dst, 16 dst/block ----------------
__global__ __launch_bounds__(256) void agg4_kernel(const ushort_t* __restrict__ h,
                                                   const float* __restrict__ as_,
                                                   const float* __restrict__ ad_,
                                                   const int* __restrict__ rowptr,
                                                   const int* __restrict__ srcs,
                                                   const float* __restrict__ bias,
                                                   ushort_t* __restrict__ out) {
    __shared__ float alds[4][256];
    int lane = threadIdx.x & 63, w = threadIdx.x >> 6;
    int q = lane >> 4, cl = lane & 15;
    int n = blockIdx.x * 16 + w * 4 + q;
    if (n >= N_NODES) return;
    int start = rowptr[n];
    int deg = rowptr[n + 1] - start;

    float4 adv = *(const float4*)(ad_ + n * 4);
    float ad4[4] = {adv.x, adv.y, adv.z, adv.w};

    float mx[4] = {-1e30f, -1e30f, -1e30f, -1e30f};
    float dn[4] = {0.f, 0.f, 0.f, 0.f};
    int s0reg = 0;
    {
        float vst[4] = {-1e30f, -1e30f, -1e30f, -1e30f};
        if (deg > 0) s0reg = srcs[start + min(cl, deg - 1)];
        if (cl < deg) {
            float4 av = *(const float4*)(as_ + s0reg * 4);
            float vv[4] = {av.x + ad4[0], av.y + ad4[1], av.z + ad4[2], av.w + ad4[3]};
#pragma unroll
            for (int hh = 0; hh < 4; ++hh) {
                float v = vv[hh] > 0.f ? vv[hh] : 0.2f * vv[hh];
                vst[hh] = v; mx[hh] = v; dn[hh] = 1.f;
            }
        }
        *(float4*)&alds[w][lane * 4] = make_float4(vst[0], vst[1], vst[2], vst[3]);
        for (int j = cl + 16; j < deg; j += 16) {
            int s = srcs[start + j];
            float4 av = *(const float4*)(as_ + s * 4);
            float vv[4] = {av.x + ad4[0], av.y + ad4[1], av.z + ad4[2], av.w + ad4[3]};
#pragma unroll
            for (int hh = 0; hh < 4; ++hh) {
                float v = vv[hh] > 0.f ? vv[hh] : 0.2f * vv[hh];
                float mn = fmaxf(mx[hh], v);
                dn[hh] = dn[hh] * __expf(mx[hh] - mn) + __expf(v - mn);
                mx[hh] = mn;
            }
        }
    }
    float mloc[4] = {mx[0], mx[1], mx[2], mx[3]};
#pragma unroll
    for (int off = 1; off < 16; off <<= 1)
#pragma unroll
        for (int hh = 0; hh < 4; ++hh) mx[hh] = fmaxf(mx[hh], __shfl_xor(mx[hh], off, 64));
#pragma unroll
    for (int hh = 0; hh < 4; ++hh) dn[hh] *= __expf(mloc[hh] - mx[hh]);
#pragma unroll
    for (int off = 1; off < 16; off <<= 1)
#pragma unroll
        for (int hh = 0; hh < 4; ++hh) dn[hh] += __shfl_xor(dn[hh], off, 64);
    float inv[4];
#pragma unroll
    for (int hh = 0; hh < 4; ++hh) inv[hh] = dn[hh] > 0.f ? 1.f / dn[hh] : 0.f;

    {
        float4 vv = *(const float4*)&alds[w][lane * 4];
        float4 al;
        al.x = __expf(vv.x - mx[0]) * inv[0];
        al.y = __expf(vv.y - mx[1]) * inv[1];
        al.z = __expf(vv.z - mx[2]) * inv[2];
        al.w = __expf(vv.w - mx[3]) * inv[3];
        *(float4*)&alds[w][lane * 4] = al;
    }

    int hd = cl >> 2;
    float acc[16];
#pragma unroll
    for (int k = 0; k < 16; ++k) acc[k] = 0.f;
    for (int chunk = 0; chunk < deg || chunk == 0; chunk += 16) {
        int s = s0reg;
        if (chunk > 0) {
            int j = chunk + cl;
            float4 al = make_float4(0.f, 0.f, 0.f, 0.f);
            s = srcs[start + min(j, deg - 1)];
            if (j < deg) {
                float4 av = *(const float4*)(as_ + s * 4);
                float vv[4] = {av.x + ad4[0], av.y + ad4[1], av.z + ad4[2], av.w + ad4[3]};
                float a4[4];
#pragma unroll
                for (int hh = 0; hh < 4; ++hh) {
                    float v = vv[hh] > 0.f ? vv[hh] : 0.2f * vv[hh];
                    a4[hh] = __expf(v - mx[hh]) * inv[hh];
                }
                al = make_float4(a4[0], a4[1], a4[2], a4[3]);
            }
            *(float4*)&alds[w][lane * 4] = al;
        }
        int cnt = min(16, deg - chunk);
        if (cnt < 0) cnt = 0;
#pragma unroll 4
        for (int e = 0; e < cnt; ++e) {
            int se = __shfl(s, q * 16 + e, 64);
            float al = alds[w][(q * 16 + e) * 4 + hd];
            const ushort_t* hr = h + (long)se * 256 + cl * 16;
            uint4 u0 = *(const uint4*)hr;
            uint4 u1 = *(const uint4*)(hr + 8);
            acc[0] += al * bflo(u0.x);  acc[1] += al * bfhi(u0.x);
            acc[2] += al * bflo(u0.y);  acc[3] += al * bfhi(u0.y);
            acc[4] += al * bflo(u0.z);  acc[5] += al * bfhi(u0.z);
            acc[6] += al * bflo(u0.w);  acc[7] += al * bfhi(u0.w);
            acc[8] += al * bflo(u1.x);  acc[9] += al * bfhi(u1.x);
            acc[10] += al * bflo(u1.y); acc[11] += al * bfhi(u1.y);
            acc[12] += al * bflo(u1.z); acc[13] += al * bfhi(u1.z);
            acc[14] += al * bflo(u1.w); acc[15] += al * bfhi(u1.w);
        }
        if (deg <= 16) break;
    }
    int c0 = cl * 16;
    uint_t ow[8];
#pragma unroll
    for (int t = 0; t < 8; ++t) {
        float lo = fmaxf(acc[t * 2] + bias[c0 + t * 2], 0.f);
        float hi = fmaxf(acc[t * 2 + 1] + bias[c0 + t * 2 + 1], 0.f);
        ow[t] = pkbf(lo, hi);
    }
    ushort_t* op = out + (long)n * 256 + c0;
    *(uint4*)op = make_uint4(ow[0], ow[1], ow[2], ow[3]);
    *(uint4*)(op + 8) = make_uint4(ow[4], ow[5], ow[6], ow[7]);
}

// ---------------- GAT aggregation H=1: octant (8 lanes) per dst, 32 dst/block ----------------
__global__ __launch_bounds__(256) void agg1_kernel(const ushort_t* __restrict__ h,
                                                   const float* __restrict__ as_,
                                                   const float* __restrict__ ad_,
                                                   const int* __restrict__ rowptr,
                                                   const int* __restrict__ srcs,
                                                   const float* __restrict__ bias,
                                                   ushort_t* __restrict__ out) {
    __shared__ float alds1[4][64];
    int lane = threadIdx.x & 63, w = threadIdx.x >> 6;
    int o = lane >> 3, cl = lane & 7;
    int n = blockIdx.x * 32 + w * 8 + o;
    if (n >= N_NODES) return;
    int start = rowptr[n];
    int deg = rowptr[n + 1] - start;
    float adn = ad_[n];

    float mx = -1e30f, dn = 0.f;
    int s0reg = 0;
    {
        float vst = -1e30f;
        if (deg > 0) s0reg = srcs[start + min(cl, deg - 1)];
        if (cl < deg) {
            float v = as_[s0reg] + adn;
            v = v > 0.f ? v : 0.2f * v;
            vst = v; mx = v; dn = 1.f;
        }
        alds1[w][lane] = vst;
        for (int j = cl + 8; j < deg; j += 8) {
            int s = srcs[start + j];
            float v = as_[s] + adn;
            v = v > 0.f ? v : 0.2f * v;
            float mn = fmaxf(mx, v);
            dn = dn * __expf(mx - mn) + __expf(v - mn);
            mx = mn;
        }
    }
    float mloc = mx;
#pragma unroll
    for (int off = 1; off < 8; off <<= 1) mx = fmaxf(mx, __shfl_xor(mx, off, 64));
    dn *= __expf(mloc - mx);
#pragma unroll
    for (int off = 1; off < 8; off <<= 1) dn += __shfl_xor(dn, off, 64);
    float inv = dn > 0.f ? 1.f / dn : 0.f;

    alds1[w][lane] = __expf(alds1[w][lane] - mx) * inv;

    float acc[8] = {0.f, 0.f, 0.f, 0.f, 0.f, 0.f, 0.f, 0.f};
    for (int chunk = 0; chunk < deg || chunk == 0; chunk += 8) {
        int s = s0reg;
        if (chunk > 0) {
            int j = chunk + cl;
            float al = 0.f;
            s = srcs[start + min(j, deg - 1)];
            if (j < deg) {
                float v = as_[s] + adn;
                v = v > 0.f ? v : 0.2f * v;
                al = __expf(v - mx) * inv;
            }
            alds1[w][lane] = al;
        }
        int cnt = min(8, deg - chunk);
        if (cnt < 0) cnt = 0;
#pragma unroll 4
        for (int e = 0; e < cnt; ++e) {
            int se = __shfl(s, o * 8 + e, 64);
            float al = alds1[w][o * 8 + e];
            const ushort_t* hr = h + (long)se * 64 + cl * 8;
            uint4 u = *(const uint4*)hr;
            acc[0] += al * bflo(u.x); acc[1] += al * bfhi(u.x);
            acc[2] += al * bflo(u.y); acc[3] += al * bfhi(u.y);
            acc[4] += al * bflo(u.z); acc[5] += al * bfhi(u.z);
            acc[6] += al * bflo(u.w); acc[7] += al * bfhi(u.w);
        }
        if (deg <= 8) break;
    }
    int c0 = cl * 8;
    uint_t ow[4];
#pragma unroll
    for (int t = 0; t < 4; ++t) {
        float lo = fmaxf(acc[t * 2] + bias[c0 + t * 2], 0.f);
        float hi = fmaxf(acc[t * 2 + 1] + bias[c0 + t * 2 + 1], 0.f);
        ow[t] = pkbf(lo, hi);
    }
    *(uint4*)(out + (long)n * 64 + c0) = make_uint4(ow[0], ow[1], ow[2], ow[3]);
}

// ---------------- BatchNorm stats on bf16, coalesced ----------------
template<int C>
__global__ __launch_bounds__(256) void bn_stats_bf16(const ushort_t* __restrict__ x,
                                                     float* __restrict__ stats) {
    const int GROUPS = C / 8;
    const int RS = 256 / GROUPS;
    int tid = threadIdx.x;
    int cg_ = tid % GROUPS;
    int rs = tid / GROUPS;
    float s[8], s2[8];
#pragma unroll
    for (int k = 0; k < 8; ++k) { s[k] = 0.f; s2[k] = 0.f; }
    for (int n = blockIdx.x * RS + rs; n < N_NODES; n += gridDim.x * RS) {
        uint4 u = *(const uint4*)(x + (long)n * C + cg_ * 8);
        float f[8] = {bflo(u.x), bfhi(u.x), bflo(u.y), bfhi(u.y),
                      bflo(u.z), bfhi(u.z), bflo(u.w), bfhi(u.w)};
#pragma unroll
        for (int k = 0; k < 8; ++k) { s[k] += f[k]; s2[k] += f[k] * f[k]; }
    }
    __shared__ float red[256][16];
#pragma unroll
    for (int k = 0; k < 8; ++k) { red[tid][k] = s[k]; red[tid][8 + k] = s2[k]; }
    __syncthreads();
    if (tid < C) {
        int g = tid >> 3, k = tid & 7;
        float a = 0.f, b = 0.f;
        for (int r = 0; r < RS; ++r) {
            a += red[g + r * GROUPS][k];
            b += red[g + r * GROUPS][8 + k];
        }
        atomicAdd(&stats[tid], a);
        atomicAdd(&stats[256 + tid], b);
    }
}

// ---------------- pool (BN affine fused) + FC, one block per graph ----------------
__global__ __launch_bounds__(256) void pool_fc_kernel(const ushort_t* __restrict__ h,
                                                      const int* __restrict__ goff,
                                                      const float* __restrict__ stats,
                                                      const float* __restrict__ g3,
                                                      const float* __restrict__ be3,
                                                      const float* __restrict__ fcW,
                                                      const float* __restrict__ fcb,
                                                      float* __restrict__ out) {
    int g = blockIdx.x;
    int c = threadIdx.x & 63;
    int ty = threadIdx.x >> 6;
    int s = goff[g], e = goff[g + 1];
    float sum = 0.f;
    for (int n = s + ty; n < e; n += 4) sum += bflo((uint_t)h[(long)n * 64 + c]);
    __shared__ float red[4][64];
    __shared__ float pv[64];
    red[ty][c] = sum;
    __syncthreads();
    if (ty == 0) {
        float tot = red[0][c] + red[1][c] + red[2][c] + red[3][c];
        float v = tot / fmaxf((float)(e - s), 1.f);
        float m = stats[c] * (1.f / N_NODES);
        float var = fmaxf(stats[256 + c] * (1.f / N_NODES) - m * m, 0.f);
        pv[c] = (v - m) * rsqrtf(var + EPS_BN) * g3[c] + be3[c];
    }
    __syncthreads();
    if (threadIdx.x < 10) {
        int j = threadIdx.x;
        float acc = fcb[j];
#pragma unroll
        for (int k = 0; k < 64; ++k) acc += pv[k] * fcW[k * 10 + j];
        out[g * 10 + j] = acc;
    }
}

extern "C" void kernel_launch(void* const* d_in, const int* in_sizes, int n_in,
                              void* d_out, int out_size, void* d_ws, size_t ws_size,
                              hipStream_t stream) {
    const float* x      = (const float*)d_in[0];
    const int*   ei     = (const int*)d_in[1];
    const int*   batch  = (const int*)d_in[2];
    const float* W1     = (const float*)d_in[3];
    const float* a_src1 = (const float*)d_in[4];
    const float* a_dst1 = (const float*)d_in[5];
    const float* b1     = (const float*)d_in[6];
    const float* g1     = (const float*)d_in[7];
    const float* be1    = (const float*)d_in[8];
    const float* W2     = (const float*)d_in[9];
    const float* a_src2 = (const float*)d_in[10];
    const float* a_dst2 = (const float*)d_in[11];
    const float* b2     = (const float*)d_in[12];
    const float* g2     = (const float*)d_in[13];
    const float* be2    = (const float*)d_in[14];
    const float* W3     = (const float*)d_in[15];
    const float* a_src3 = (const float*)d_in[16];
    const float* a_dst3 = (const float*)d_in[17];
    const float* b3     = (const float*)d_in[18];
    const float* g3     = (const float*)d_in[19];
    const float* be3    = (const float*)d_in[20];
    const float* fcW    = (const float*)d_in[21];
    const float* fcb    = (const float*)d_in[22];
    float* out = (float*)d_out;

    const size_t N = N_NODES, E = NUM_E;
    ushort_t* hbf    = (ushort_t*)d_ws;                 // [N,256] bf16 GEMM output
    ushort_t* hagg   = hbf + N * 256;                   // [N,256] bf16 agg output (pre-BN)
    ushort_t* xbf    = hagg + N * 256;                  // [N,128] bf16 x
    ushort_t* w1t    = xbf + N * 128;                   // [256][128]
    ushort_t* w2t    = w1t + 256 * 128;                 // [256][256]
    ushort_t* w3t    = w2t + 256 * 256;                 // [64][256]
    float*    as_    = (float*)(w3t + 64 * 256 + 128);  // [N,4]
    float*    ad_    = as_ + N * 4;                     // [N,4]
    int*      deg    = (int*)(ad_ + N * 4);             // [N] + fill [N] right after
    int*      fill   = deg + N;                         // [N]
    float*    statsA = (float*)(fill + N);              // [512]
    float*    statsB = statsA + 512;                    // [512]
    float*    statsC = statsB + 512;                    // [512]
    int*      rowptr = (int*)(statsC + 512);            // [N+1]
    int*      srcs   = rowptr + (N + 1);                // [E]
    int*      bsum   = srcs + E;                        // [256]
    int*      goff   = bsum + 256;                      // [65]

    // ---- one cooperative setup dispatch: zero + cvt + prep + offsets + CSR ----
    {
        void* args[] = {(void*)&ei, (void*)&batch, (void*)&x, (void*)&W1, (void*)&W2, (void*)&W3,
                        (void*)&xbf, (void*)&w1t, (void*)&w2t, (void*)&w3t,
                        (void*)&deg, (void*)&statsA, (void*)&rowptr, (void*)&srcs,
                        (void*)&bsum, (void*)&goff};
        hipLaunchCooperativeKernel((void*)setup_kernel, dim3(1024), dim3(256), args, 0, stream);
    }

    const int GB = (N_NODES + 127) / 128;  // 391

    // ---- layer 1: A = xbf (identity affine), BN=128 (2 heads/block) ----
    gemm_fused_kernel<128, 256, 128><<<dim3(GB, 2), 256, 0, stream>>>(
        xbf, w1t, hbf, nullptr, nullptr, nullptr, a_src1, a_dst1, as_, ad_);
    agg4_kernel<<<(N_NODES + 15) / 16, 256, 0, stream>>>(hbf, as_, ad_, rowptr, srcs, b1, hagg);
    bn_stats_bf16<256><<<128, 256, 0, stream>>>(hagg, statsA);

    // ---- layer 2 ----
    gemm_fused_kernel<256, 256, 128><<<dim3(GB, 2), 256, 0, stream>>>(
        hagg, w2t, hbf, statsA, g1, be1, a_src2, a_dst2, as_, ad_);
    agg4_kernel<<<(N_NODES + 15) / 16, 256, 0, stream>>>(hbf, as_, ad_, rowptr, srcs, b2, hagg);
    bn_stats_bf16<256><<<128, 256, 0, stream>>>(hagg, statsB);

    // ---- layer 3 ----
    gemm_fused_kernel<256, 64, 64><<<dim3(GB, 1), 256, 0, stream>>>(
        hagg, w3t, hbf, statsB, g2, be2, a_src3, a_dst3, as_, ad_);
    agg1_kernel<<<(N_NODES + 31) / 32, 256, 0, stream>>>(hbf, as_, ad_, rowptr, srcs, b3, hagg);
    bn_stats_bf16<64><<<128, 256, 0, stream>>>(hagg, statsC);

    // ---- pool + BN3 affine + FC in one ----
    pool_fc_kernel<<<NUM_GRAPHS, 256, 0, stream>>>(hagg, goff, statsC, g3, be3, fcW, fcb, out);
}

// Round 10
// 513.376 us; speedup vs baseline: 1.9950x; 1.9950x over previous
//
#include <hip/hip_runtime.h>
#include <hip/hip_bf16.h>

#define N_NODES 50000
#define NUM_E   800000
#define EPS_BN  1e-5f
#define NUM_GRAPHS 64

typedef __attribute__((ext_vector_type(8))) short bf16x8;
typedef __attribute__((ext_vector_type(4))) float f32x4;
typedef unsigned short ushort_t;
typedef unsigned int uint_t;

static __device__ __forceinline__ unsigned short f2bf(float f) {
    unsigned int u = __float_as_uint(f);
    u += 0x7fffu + ((u >> 16) & 1u);   // RNE
    return (unsigned short)(u >> 16);
}
// packed f32x2 -> bf16x2 (v_cvt_pk_bf16_f32), lo in low 16 bits
static __device__ __forceinline__ uint_t pkbf(float lo, float hi) {
    __hip_bfloat162 t = __float22bfloat162_rn(make_float2(lo, hi));
    return *(uint_t*)&t;
}
static __device__ __forceinline__ float bflo(uint_t u) { return __uint_as_float(u << 16); }
static __device__ __forceinline__ float bfhi(uint_t u) { return __uint_as_float(u & 0xffff0000u); }

// ---------------- CSR build (split chain: launch gaps << grid.sync cost, measured R9) ----------------
__global__ void hist_kernel(const int* __restrict__ ei, int* __restrict__ deg) {
    int e = blockIdx.x * blockDim.x + threadIdx.x;
    if (e >= NUM_E) return;
    atomicAdd(&deg[ei[NUM_E + e]], 1);
}

__global__ void scan_local_kernel(const int* __restrict__ deg, int* __restrict__ rowptr,
                                  int* __restrict__ bsum) {
    __shared__ int ws[4];
    int b = blockIdx.x, t = threadIdx.x;
    int i = b * 256 + t;
    int lane = t & 63, wv = t >> 6;
    int v = (i < N_NODES) ? deg[i] : 0;
    int incl = v;
#pragma unroll
    for (int off = 1; off < 64; off <<= 1) {
        int u = __shfl_up(incl, off, 64);
        if (lane >= off) incl += u;
    }
    if (lane == 63) ws[wv] = incl;
    __syncthreads();
    if (t == 0) {
        int s = 0;
#pragma unroll
        for (int k = 0; k < 4; ++k) { int x = ws[k]; ws[k] = s; s += x; }
        bsum[b] = s;
    }
    __syncthreads();
    if (i < N_NODES) rowptr[i + 1] = ws[wv] + incl;
}

__global__ void scan_sums_kernel(int* __restrict__ bsum, int nb) {
    __shared__ int ws[4];
    int t = threadIdx.x;
    int lane = t & 63, wv = t >> 6;
    int v = (t < nb) ? bsum[t] : 0;
    int incl = v;
#pragma unroll
    for (int off = 1; off < 64; off <<= 1) {
        int u = __shfl_up(incl, off, 64);
        if (lane >= off) incl += u;
    }
    if (lane == 63) ws[wv] = incl;
    __syncthreads();
    if (t == 0) {
        int s = 0;
#pragma unroll
        for (int k = 0; k < 4; ++k) { int x = ws[k]; ws[k] = s; s += x; }
    }
    __syncthreads();
    if (t < nb) bsum[t] = ws[wv] + incl - v;   // exclusive
}

__global__ void scan_add_kernel(int* __restrict__ rowptr, const int* __restrict__ bsum) {
    int b = blockIdx.x, t = threadIdx.x;
    int i = b * 256 + t;
    if (i < N_NODES) rowptr[i + 1] += bsum[b];
    if (b == 0 && t == 0) rowptr[0] = 0;
}

__global__ void scatter_kernel(const int* __restrict__ ei, const int* __restrict__ rowptr,
                               int* __restrict__ fill, int* __restrict__ srcs) {
    int e = blockIdx.x * blockDim.x + threadIdx.x;
    if (e >= NUM_E) return;
    int dst = ei[NUM_E + e];
    int pos = rowptr[dst] + atomicAdd(&fill[dst], 1);
    srcs[pos] = ei[e];
}

__global__ void batch_offsets_kernel(const int* __restrict__ batch, int* __restrict__ goff) {
    int g = threadIdx.x;
    if (g > NUM_GRAPHS) return;
    int lo = 0, hi = N_NODES;
    while (lo < hi) {
        int mid = (lo + hi) >> 1;
        if (batch[mid] < g) lo = mid + 1; else hi = mid;
    }
    goff[g] = lo;
}

// ---------------- prep: W transpose->bf16 AND x->bf16 in one dispatch ----------------
__global__ void prep_all_kernel(const float* __restrict__ W1, const float* __restrict__ W2,
                                const float* __restrict__ W3, const float* __restrict__ x,
                                ushort_t* __restrict__ w1t, ushort_t* __restrict__ w2t,
                                ushort_t* __restrict__ w3t, ushort_t* __restrict__ xbf) {
    const int S1 = 128 * 256, S2 = 256 * 256, S3 = 256 * 64;
    const int SW = S1 + S2 + S3;                 // 81920
    const int SX = N_NODES * 128 / 4;            // 1.6M float4 units
    int i = blockIdx.x * blockDim.x + threadIdx.x;
    if (i < SX) {
        float4 v = ((const float4*)x)[i];
        ((uint2*)xbf)[i] = make_uint2(pkbf(v.x, v.y), pkbf(v.z, v.w));
    } else if (i < SX + SW) {
        int j = i - SX;
        if (j < S1) {
            int k = j / 256, n = j % 256;
            w1t[n * 128 + k] = f2bf(W1[j]);
        } else if (j < S1 + S2) {
            int jj = j - S1; int k = jj / 256, n = jj % 256;
            w2t[n * 256 + k] = f2bf(W2[jj]);
        } else {
            int jj = j - S1 - S2; int k = jj / 64, n = jj % 64;
            w3t[n * 256 + k] = f2bf(W3[jj]);
        }
    }
}

// ---------------- fused GEMM: BN-affine(A bf16)->bf16 @ Bt^T -> h(bf16) + per-head logits ----------------
template<int K, int NFULL, int BN>
__global__ __launch_bounds__(256) void gemm_fused_kernel(const ushort_t* __restrict__ A,
                                                         const ushort_t* __restrict__ Bt,
                                                         ushort_t* __restrict__ C,
                                                         const float* __restrict__ stats,
                                                         const float* __restrict__ g,
                                                         const float* __restrict__ be,
                                                         const float* __restrict__ a_src,
                                                         const float* __restrict__ a_dst,
                                                         float* __restrict__ as_,
                                                         float* __restrict__ ad_) {
    const int NT = BN / 16;
    const int NG = BN / 64;
    __shared__ __align__(16) ushort_t As[128][40];
    __shared__ __align__(16) ushort_t Bs[BN][40];
    __shared__ __align__(16) ushort_t Cs[4][32][64];
    __shared__ __align__(16) float aff_a[K], aff_b[K];
    __shared__ float asrc_s[BN], adst_s[BN];
    int tid = threadIdx.x;
    int lane = tid & 63, w = tid >> 6;
    int row0 = blockIdx.x * 128, col0 = blockIdx.y * BN;
    int m_l = lane & 15, q = lane >> 4;

    for (int c = tid; c < K; c += 256) {
        float a = 1.f, b = 0.f;
        if (stats) {
            float m = stats[c] * (1.f / N_NODES);
            float var = fmaxf(stats[256 + c] * (1.f / N_NODES) - m * m, 0.f);
            float rs = rsqrtf(var + EPS_BN) * g[c];
            a = rs; b = be[c] - m * rs;
        }
        aff_a[c] = a; aff_b[c] = b;
    }
    if (tid < BN) {
        asrc_s[tid] = a_src[col0 + tid];
        adst_s[tid] = a_dst[col0 + tid];
    }
    __syncthreads();

    f32x4 acc[2][NT];
#pragma unroll
    for (int r = 0; r < 2; ++r)
#pragma unroll
        for (int c = 0; c < NT; ++c) acc[r][c] = (f32x4){0.f, 0.f, 0.f, 0.f};

    int ar = tid >> 1, ako = (tid & 1) * 16;

    for (int k0 = 0; k0 < K; k0 += 32) {
        uint_t ow[8];
        int gr = row0 + ar;
        uint4 u0 = make_uint4(0, 0, 0, 0), u1 = make_uint4(0, 0, 0, 0);
        if (gr < N_NODES) {
            const ushort_t* ap = A + (long)gr * K + k0 + ako;
            u0 = *(const uint4*)ap;
            u1 = *(const uint4*)(ap + 8);
        }
        uint_t uu[8] = {u0.x, u0.y, u0.z, u0.w, u1.x, u1.y, u1.z, u1.w};
#pragma unroll
        for (int t = 0; t < 8; ++t) {
            int k = k0 + ako + t * 2;
            float lo = bflo(uu[t]) * aff_a[k] + aff_b[k];
            float hi = bfhi(uu[t]) * aff_a[k + 1] + aff_b[k + 1];
            ow[t] = pkbf(lo, hi);
        }
        if constexpr (BN == 128) {
            int br = tid >> 1, bko = (tid & 1) * 16;
            const ushort_t* bp = Bt + (long)(col0 + br) * K + k0 + bko;
            uint4 b0 = *(const uint4*)bp;
            uint4 b1 = *(const uint4*)(bp + 8);
            *(uint4*)&As[ar][ako] = make_uint4(ow[0], ow[1], ow[2], ow[3]);
            *(uint4*)&As[ar][ako + 8] = make_uint4(ow[4], ow[5], ow[6], ow[7]);
            *(uint4*)&Bs[br][bko] = b0;
            *(uint4*)&Bs[br][bko + 8] = b1;
        } else {
            int br = tid >> 2, bko = (tid & 3) * 8;
            uint4 bv = *(const uint4*)(Bt + (long)(col0 + br) * K + k0 + bko);
            *(uint4*)&As[ar][ako] = make_uint4(ow[0], ow[1], ow[2], ow[3]);
            *(uint4*)&As[ar][ako + 8] = make_uint4(ow[4], ow[5], ow[6], ow[7]);
            *(uint4*)&Bs[br][bko] = bv;
        }
        __syncthreads();

        bf16x8 af[2];
#pragma unroll
        for (int r = 0; r < 2; ++r)
            af[r] = *(const bf16x8*)&As[w * 32 + r * 16 + m_l][q * 8];
#pragma unroll
        for (int c = 0; c < NT; ++c) {
            bf16x8 bf = *(const bf16x8*)&Bs[c * 16 + m_l][q * 8];
#pragma unroll
            for (int r = 0; r < 2; ++r)
                acc[r][c] = __builtin_amdgcn_mfma_f32_16x16x32_bf16(af[r], bf, acc[r][c], 0, 0, 0);
        }
        __syncthreads();
    }

    const int H = NFULL / 64;
#pragma unroll
    for (int gblk = 0; gblk < NG; ++gblk) {
        int hidx = blockIdx.y * NG + gblk;
        int colg = col0 + gblk * 64;
#pragma unroll
        for (int r = 0; r < 2; ++r)
#pragma unroll
            for (int cc = 0; cc < 4; ++cc)
#pragma unroll
                for (int i = 0; i < 4; ++i)
                    Cs[w][r * 16 + q * 4 + i][cc * 16 + m_l] = f2bf(acc[r][gblk * 4 + cc][i]);
        // same-wave LDS RAW: in-order DS pipe, no barrier needed
#pragma unroll
        for (int j = 0; j < 4; ++j) {
            int flat = j * 64 + lane;
            int lr = flat >> 3, chg = flat & 7;
            int gr = row0 + w * 32 + lr;
            uint4 u = *(uint4*)&Cs[w][lr][chg * 8];
            float f0 = bflo(u.x), f1 = bfhi(u.x), f2 = bflo(u.y), f3 = bfhi(u.y);
            float f4 = bflo(u.z), f5 = bfhi(u.z), f6 = bflo(u.w), f7 = bfhi(u.w);
            int cb = gblk * 64 + chg * 8;
            float s1 = f0 * asrc_s[cb] + f1 * asrc_s[cb + 1] + f2 * asrc_s[cb + 2] + f3 * asrc_s[cb + 3]
                     + f4 * asrc_s[cb + 4] + f5 * asrc_s[cb + 5] + f6 * asrc_s[cb + 6] + f7 * asrc_s[cb + 7];
            float s2 = f0 * adst_s[cb] + f1 * adst_s[cb + 1] + f2 * adst_s[cb + 2] + f3 * adst_s[cb + 3]
                     + f4 * adst_s[cb + 4] + f5 * adst_s[cb + 5] + f6 * adst_s[cb + 6] + f7 * adst_s[cb + 7];
#pragma unroll
            for (int o = 1; o < 8; o <<= 1) {
                s1 += __shfl_xor(s1, o, 64);
                s2 += __shfl_xor(s2, o, 64);
            }
            if (gr < N_NODES) {
                *(uint4*)(C + (long)gr * NFULL + colg + chg * 8) = u;
                if ((lane & 7) == 0) {
                    as_[gr * H + hidx] = s1;
                    ad_[gr * H + hidx] = s2;
                }
            }
        }
    }
}

// ---------------- GAT aggregation H=4: quarter-wave (16 lanes) per dst, 16 dst/block ----------------
__global__ __launch_bounds__(256) void agg4_kernel(const ushort_t* __restrict__ h,
                                                   const float* __restrict__ as_,
                                                   const float* __restrict__ ad_,
                                                   const int* __restrict__ rowptr,
                                                   const int* __restrict__ srcs,
                                                   const float* __restrict__ bias,
                                                   ushort_t* __restrict__ out) {
    __shared__ float alds[4][256];
    int lane = threadIdx.x & 63, w = threadIdx.x >> 6;
    int q = lane >> 4, cl = lane & 15;
    int n = blockIdx.x * 16 + w * 4 + q;
    if (n >= N_NODES) return;
    int start = rowptr[n];
    int deg = rowptr[n + 1] - start;

    float4 adv = *(const float4*)(ad_ + n * 4);
    float ad4[4] = {adv.x, adv.y, adv.z, adv.w};

    float mx[4] = {-1e30f, -1e30f, -1e30f, -1e30f};
    float dn[4] = {0.f, 0.f, 0.f, 0.f};
    int s0reg = 0;
    {
        float vst[4] = {-1e30f, -1e30f, -1e30f, -1e30f};
        if (deg > 0) s0reg = srcs[start + min(cl, deg - 1)];
        if (cl < deg) {
            float4 av = *(const float4*)(as_ + s0reg * 4);
            float vv[4] = {av.x + ad4[0], av.y + ad4[1], av.z + ad4[2], av.w + ad4[3]};
#pragma unroll
            for (int hh = 0; hh < 4; ++hh) {
                float v = vv[hh] > 0.f ? vv[hh] : 0.2f * vv[hh];
                vst[hh] = v; mx[hh] = v; dn[hh] = 1.f;
            }
        }
        *(float4*)&alds[w][lane * 4] = make_float4(vst[0], vst[1], vst[2], vst[3]);
        for (int j = cl + 16; j < deg; j += 16) {
            int s = srcs[start + j];
            float4 av = *(const float4*)(as_ + s * 4);
            float vv[4] = {av.x + ad4[0], av.y + ad4[1], av.z + ad4[2], av.w + ad4[3]};
#pragma unroll
            for (int hh = 0; hh < 4; ++hh) {
                float v = vv[hh] > 0.f ? vv[hh] : 0.2f * vv[hh];
                float mn = fmaxf(mx[hh], v);
                dn[hh] = dn[hh] * __expf(mx[hh] - mn) + __expf(v - mn);
                mx[hh] = mn;
            }
        }
    }
    float mloc[4] = {mx[0], mx[1], mx[2], mx[3]};
#pragma unroll
    for (int off = 1; off < 16; off <<= 1)
#pragma unroll
        for (int hh = 0; hh < 4; ++hh) mx[hh] = fmaxf(mx[hh], __shfl_xor(mx[hh], off, 64));
#pragma unroll
    for (int hh = 0; hh < 4; ++hh) dn[hh] *= __expf(mloc[hh] - mx[hh]);
#pragma unroll
    for (int off = 1; off < 16; off <<= 1)
#pragma unroll
        for (int hh = 0; hh < 4; ++hh) dn[hh] += __shfl_xor(dn[hh], off, 64);
    float inv[4];
#pragma unroll
    for (int hh = 0; hh < 4; ++hh) inv[hh] = dn[hh] > 0.f ? 1.f / dn[hh] : 0.f;

    {
        float4 vv = *(const float4*)&alds[w][lane * 4];
        float4 al;
        al.x = __expf(vv.x - mx[0]) * inv[0];
        al.y = __expf(vv.y - mx[1]) * inv[1];
        al.z = __expf(vv.z - mx[2]) * inv[2];
        al.w = __expf(vv.w - mx[3]) * inv[3];
        *(float4*)&alds[w][lane * 4] = al;
    }

    int hd = cl >> 2;
    float acc[16];
#pragma unroll
    for (int k = 0; k < 16; ++k) acc[k] = 0.f;
    for (int chunk = 0; chunk < deg || chunk == 0; chunk += 16) {
        int s = s0reg;
        if (chunk > 0) {
            int j = chunk + cl;
            float4 al = make_float4(0.f, 0.f, 0.f, 0.f);
            s = srcs[start + min(j, deg - 1)];
            if (j < deg) {
                float4 av = *(const float4*)(as_ + s * 4);
                float vv[4] = {av.x + ad4[0], av.y + ad4[1], av.z + ad4[2], av.w + ad4[3]};
                float a4[4];
#pragma unroll
                for (int hh = 0; hh < 4; ++hh) {
                    float v = vv[hh] > 0.f ? vv[hh] : 0.2f * vv[hh];
                    a4[hh] = __expf(v - mx[hh]) * inv[hh];
                }
                al = make_float4(a4[0], a4[1], a4[2], a4[3]);
            }
            *(float4*)&alds[w][lane * 4] = al;
        }
        int cnt = min(16, deg - chunk);
        if (cnt < 0) cnt = 0;
#pragma unroll 4
        for (int e = 0; e < cnt; ++e) {
            int se = __shfl(s, q * 16 + e, 64);
            float al = alds[w][(q * 16 + e) * 4 + hd];
            const ushort_t* hr = h + (long)se * 256 + cl * 16;
            uint4 u0 = *(const uint4*)hr;
            uint4 u1 = *(const uint4*)(hr + 8);
            acc[0] += al * bflo(u0.x);  acc[1] += al * bfhi(u0.x);
            acc[2] += al * bflo(u0.y);  acc[3] += al * bfhi(u0.y);
            acc[4] += al * bflo(u0.z);  acc[5] += al * bfhi(u0.z);
            acc[6] += al * bflo(u0.w);  acc[7] += al * bfhi(u0.w);
            acc[8] += al * bflo(u1.x);  acc[9] += al * bfhi(u1.x);
            acc[10] += al * bflo(u1.y); acc[11] += al * bfhi(u1.y);
            acc[12] += al * bflo(u1.z); acc[13] += al * bfhi(u1.z);
            acc[14] += al * bflo(u1.w); acc[15] += al * bfhi(u1.w);
        }
        if (deg <= 16) break;
    }
    int c0 = cl * 16;
    uint_t ow[8];
#pragma unroll
    for (int t = 0; t < 8; ++t) {
        float lo = fmaxf(acc[t * 2] + bias[c0 + t * 2], 0.f);
        float hi = fmaxf(acc[t * 2 + 1] + bias[c0 + t * 2 + 1], 0.f);
        ow[t] = pkbf(lo, hi);
    }
    ushort_t* op = out + (long)n * 256 + c0;
    *(uint4*)op = make_uint4(ow[0], ow[1], ow[2], ow[3]);
    *(uint4*)(op + 8) = make_uint4(ow[4], ow[5], ow[6], ow[7]);
}

// ---------------- GAT aggregation H=1: octant (8 lanes) per dst, 32 dst/block ----------------
__global__ __launch_bounds__(256) void agg1_kernel(const ushort_t* __restrict__ h,
                                                   const float* __restrict__ as_,
                                                   const float* __restrict__ ad_,
                                                   const int* __restrict__ rowptr,
                                                   const int* __restrict__ srcs,
                                                   const float* __restrict__ bias,
                                                   ushort_t* __restrict__ out) {
    __shared__ float alds1[4][64];
    int lane = threadIdx.x & 63, w = threadIdx.x >> 6;
    int o = lane >> 3, cl = lane & 7;
    int n = blockIdx.x * 32 + w * 8 + o;
    if (n >= N_NODES) return;
    int start = rowptr[n];
    int deg = rowptr[n + 1] - start;
    float adn = ad_[n];

    float mx = -1e30f, dn = 0.f;
    int s0reg = 0;
    {
        float vst = -1e30f;
        if (deg > 0) s0reg = srcs[start + min(cl, deg - 1)];
        if (cl < deg) {
            float v = as_[s0reg] + adn;
            v = v > 0.f ? v : 0.2f * v;
            vst = v; mx = v; dn = 1.f;
        }
        alds1[w][lane] = vst;
        for (int j = cl + 8; j < deg; j += 8) {
            int s = srcs[start + j];
            float v = as_[s] + adn;
            v = v > 0.f ? v : 0.2f * v;
            float mn = fmaxf(mx, v);
            dn = dn * __expf(mx - mn) + __expf(v - mn);
            mx = mn;
        }
    }
    float mloc = mx;
#pragma unroll
    for (int off = 1; off < 8; off <<= 1) mx = fmaxf(mx, __shfl_xor(mx, off, 64));
    dn *= __expf(mloc - mx);
#pragma unroll
    for (int off = 1; off < 8; off <<= 1) dn += __shfl_xor(dn, off, 64);
    float inv = dn > 0.f ? 1.f / dn : 0.f;

    alds1[w][lane] = __expf(alds1[w][lane] - mx) * inv;

    float acc[8] = {0.f, 0.f, 0.f, 0.f, 0.f, 0.f, 0.f, 0.f};
    for (int chunk = 0; chunk < deg || chunk == 0; chunk += 8) {
        int s = s0reg;
        if (chunk > 0) {
            int j = chunk + cl;
            float al = 0.f;
            s = srcs[start + min(j, deg - 1)];
            if (j < deg) {
                float v = as_[s] + adn;
                v = v > 0.f ? v : 0.2f * v;
                al = __expf(v - mx) * inv;
            }
            alds1[w][lane] = al;
        }
        int cnt = min(8, deg - chunk);
        if (cnt < 0) cnt = 0;
#pragma unroll 4
        for (int e = 0; e < cnt; ++e) {
            int se = __shfl(s, o * 8 + e, 64);
            float al = alds1[w][o * 8 + e];
            const ushort_t* hr = h + (long)se * 64 + cl * 8;
            uint4 u = *(const uint4*)hr;
            acc[0] += al * bflo(u.x); acc[1] += al * bfhi(u.x);
            acc[2] += al * bflo(u.y); acc[3] += al * bfhi(u.y);
            acc[4] += al * bflo(u.z); acc[5] += al * bfhi(u.z);
            acc[6] += al * bflo(u.w); acc[7] += al * bfhi(u.w);
        }
        if (deg <= 8) break;
    }
    int c0 = cl * 8;
    uint_t ow[4];
#pragma unroll
    for (int t = 0; t < 4; ++t) {
        float lo = fmaxf(acc[t * 2] + bias[c0 + t * 2], 0.f);
        float hi = fmaxf(acc[t * 2 + 1] + bias[c0 + t * 2 + 1], 0.f);
        ow[t] = pkbf(lo, hi);
    }
    *(uint4*)(out + (long)n * 64 + c0) = make_uint4(ow[0], ow[1], ow[2], ow[3]);
}

// ---------------- BatchNorm stats on bf16, coalesced ----------------
template<int C>
__global__ __launch_bounds__(256) void bn_stats_bf16(const ushort_t* __restrict__ x,
                                                     float* __restrict__ stats) {
    const int GROUPS = C / 8;
    const int RS = 256 / GROUPS;
    int tid = threadIdx.x;
    int cg_ = tid % GROUPS;
    int rs = tid / GROUPS;
    float s[8], s2[8];
#pragma unroll
    for (int k = 0; k < 8; ++k) { s[k] = 0.f; s2[k] = 0.f; }
    for (int n = blockIdx.x * RS + rs; n < N_NODES; n += gridDim.x * RS) {
        uint4 u = *(const uint4*)(x + (long)n * C + cg_ * 8);
        float f[8] = {bflo(u.x), bfhi(u.x), bflo(u.y), bfhi(u.y),
                      bflo(u.z), bfhi(u.z), bflo(u.w), bfhi(u.w)};
#pragma unroll
        for (int k = 0; k < 8; ++k) { s[k] += f[k]; s2[k] += f[k] * f[k]; }
    }
    __shared__ float red[256][16];
#pragma unroll
    for (int k = 0; k < 8; ++k) { red[tid][k] = s[k]; red[tid][8 + k] = s2[k]; }
    __syncthreads();
    if (tid < C) {
        int g = tid >> 3, k = tid & 7;
        float a = 0.f, b = 0.f;
        for (int r = 0; r < RS; ++r) {
            a += red[g + r * GROUPS][k];
            b += red[g + r * GROUPS][8 + k];
        }
        atomicAdd(&stats[tid], a);
        atomicAdd(&stats[256 + tid], b);
    }
}

// ---------------- pool (BN affine fused) + FC, one block per graph ----------------
__global__ __launch_bounds__(256) void pool_fc_kernel(const ushort_t* __restrict__ h,
                                                      const int* __restrict__ goff,
                                                      const float* __restrict__ stats,
                                                      const float* __restrict__ g3,
                                                      const float* __restrict__ be3,
                                                      const float* __restrict__ fcW,
                                                      const float* __restrict__ fcb,
                                                      float* __restrict__ out) {
    int g = blockIdx.x;
    int c = threadIdx.x & 63;
    int ty = threadIdx.x >> 6;
    int s = goff[g], e = goff[g + 1];
    float sum = 0.f;
    for (int n = s + ty; n < e; n += 4) sum += bflo((uint_t)h[(long)n * 64 + c]);
    __shared__ float red[4][64];
    __shared__ float pv[64];
    red[ty][c] = sum;
    __syncthreads();
    if (ty == 0) {
        float tot = red[0][c] + red[1][c] + red[2][c] + red[3][c];
        float v = tot / fmaxf((float)(e - s), 1.f);
        float m = stats[c] * (1.f / N_NODES);
        float var = fmaxf(stats[256 + c] * (1.f / N_NODES) - m * m, 0.f);
        pv[c] = (v - m) * rsqrtf(var + EPS_BN) * g3[c] + be3[c];
    }
    __syncthreads();
    if (threadIdx.x < 10) {
        int j = threadIdx.x;
        float acc = fcb[j];
#pragma unroll
        for (int k = 0; k < 64; ++k) acc += pv[k] * fcW[k * 10 + j];
        out[g * 10 + j] = acc;
    }
}

extern "C" void kernel_launch(void* const* d_in, const int* in_sizes, int n_in,
                              void* d_out, int out_size, void* d_ws, size_t ws_size,
                              hipStream_t stream) {
    const float* x      = (const float*)d_in[0];
    const int*   ei     = (const int*)d_in[1];
    const int*   batch  = (const int*)d_in[2];
    const float* W1     = (const float*)d_in[3];
    const float* a_src1 = (const float*)d_in[4];
    const float* a_dst1 = (const float*)d_in[5];
    const float* b1     = (const float*)d_in[6];
    const float* g1     = (const float*)d_in[7];
    const float* be1    = (const float*)d_in[8];
    const float* W2     = (const float*)d_in[9];
    const float* a_src2 = (const float*)d_in[10];
    const float* a_dst2 = (const float*)d_in[11];
    const float* b2     = (const float*)d_in[12];
    const float* g2     = (const float*)d_in[13];
    const float* be2    = (const float*)d_in[14];
    const float* W3     = (const float*)d_in[15];
    const float* a_src3 = (const float*)d_in[16];
    const float* a_dst3 = (const float*)d_in[17];
    const float* b3     = (const float*)d_in[18];
    const float* g3     = (const float*)d_in[19];
    const float* be3    = (const float*)d_in[20];
    const float* fcW    = (const float*)d_in[21];
    const float* fcb    = (const float*)d_in[22];
    float* out = (float*)d_out;

    const size_t N = N_NODES, E = NUM_E;
    ushort_t* hbf    = (ushort_t*)d_ws;                 // [N,256] bf16 GEMM output
    ushort_t* hagg   = hbf + N * 256;                   // [N,256] bf16 agg output (pre-BN)
    ushort_t* xbf    = hagg + N * 256;                  // [N,128] bf16 x
    ushort_t* w1t    = xbf + N * 128;                   // [256][128]
    ushort_t* w2t    = w1t + 256 * 128;                 // [256][256]
    ushort_t* w3t    = w2t + 256 * 256;                 // [64][256]
    float*    as_    = (float*)(w3t + 64 * 256 + 128);  // [N,4]
    float*    ad_    = as_ + N * 4;                     // [N,4]
    int*      deg    = (int*)(ad_ + N * 4);             // [N]   (zero region start)
    int*      fill   = deg + N;                         // [N]
    float*    statsA = (float*)(fill + N);              // [512]
    float*    statsB = statsA + 512;                    // [512]
    float*    statsC = statsB + 512;                    // [512]
    int*      rowptr = (int*)(statsC + 512);            // [N+1]
    int*      srcs   = rowptr + (N + 1);                // [E]
    int*      bsum   = srcs + E;                        // [256]
    int*      goff   = bsum + 256;                      // [65]

    const int NB = (N_NODES + 255) / 256;  // 196

    // ---- setup: split chain (measured R9: grid.sync cooperative fusion = 5-10x slower) ----
    hipMemsetAsync(deg, 0, sizeof(int) * (2 * N + 3 * 512), stream);
    hist_kernel<<<(NUM_E + 255) / 256, 256, 0, stream>>>(ei, deg);
    scan_local_kernel<<<NB, 256, 0, stream>>>(deg, rowptr, bsum);
    scan_sums_kernel<<<1, 256, 0, stream>>>(bsum, NB);
    scan_add_kernel<<<NB, 256, 0, stream>>>(rowptr, bsum);
    scatter_kernel<<<(NUM_E + 255) / 256, 256, 0, stream>>>(ei, rowptr, fill, srcs);
    batch_offsets_kernel<<<1, 128, 0, stream>>>(batch, goff);
    prep_all_kernel<<<(N_NODES * 128 / 4 + 128 * 256 + 256 * 256 + 256 * 64 + 255) / 256, 256, 0, stream>>>(
        W1, W2, W3, x, w1t, w2t, w3t, xbf);

    const int GB = (N_NODES + 127) / 128;  // 391

    // ---- layer 1: A = xbf (identity affine), BN=128 (2 heads/block) ----
    gemm_fused_kernel<128, 256, 128><<<dim3(GB, 2), 256, 0, stream>>>(
        xbf, w1t, hbf, nullptr, nullptr, nullptr, a_src1, a_dst1, as_, ad_);
    agg4_kernel<<<(N_NODES + 15) / 16, 256, 0, stream>>>(hbf, as_, ad_, rowptr, srcs, b1, hagg);
    bn_stats_bf16<256><<<128, 256, 0, stream>>>(hagg, statsA);

    // ---- layer 2 ----
    gemm_fused_kernel<256, 256, 128><<<dim3(GB, 2), 256, 0, stream>>>(
        hagg, w2t, hbf, statsA, g1, be1, a_src2, a_dst2, as_, ad_);
    agg4_kernel<<<(N_NODES + 15) / 16, 256, 0, stream>>>(hbf, as_, ad_, rowptr, srcs, b2, hagg);
    bn_stats_bf16<256><<<128, 256, 0, stream>>>(hagg, statsB);

    // ---- layer 3 ----
    gemm_fused_kernel<256, 64, 64><<<dim3(GB, 1), 256, 0, stream>>>(
        hagg, w3t, hbf, statsB, g2, be2, a_src3, a_dst3, as_, ad_);
    agg1_kernel<<<(N_NODES + 31) / 32, 256, 0, stream>>>(hbf, as_, ad_, rowptr, srcs, b3, hagg);
    bn_stats_bf16<64><<<128, 256, 0, stream>>>(hagg, statsC);

    // ---- pool + BN3 affine + FC in one ----
    pool_fc_kernel<<<NUM_GRAPHS, 256, 0, stream>>>(hagg, goff, statsC, g3, be3, fcW, fcb, out);
}

// Round 11
// 507.293 us; speedup vs baseline: 2.0189x; 1.0120x over previous
//
#include <hip/hip_runtime.h>
#include <hip/hip_bf16.h>

#define N_NODES 50000
#define NUM_E   800000
#define EPS_BN  1e-5f
#define NUM_GRAPHS 64

typedef __attribute__((ext_vector_type(8))) short bf16x8;
typedef __attribute__((ext_vector_type(4))) float f32x4;
typedef unsigned short ushort_t;
typedef unsigned int uint_t;

static __device__ __forceinline__ unsigned short f2bf(float f) {
    unsigned int u = __float_as_uint(f);
    u += 0x7fffu + ((u >> 16) & 1u);   // RNE
    return (unsigned short)(u >> 16);
}
// packed f32x2 -> bf16x2 (v_cvt_pk_bf16_f32), lo in low 16 bits
static __device__ __forceinline__ uint_t pkbf(float lo, float hi) {
    __hip_bfloat162 t = __float22bfloat162_rn(make_float2(lo, hi));
    return *(uint_t*)&t;
}
static __device__ __forceinline__ float bflo(uint_t u) { return __uint_as_float(u << 16); }
static __device__ __forceinline__ float bfhi(uint_t u) { return __uint_as_float(u & 0xffff0000u); }

// ---------------- CSR build (split chain: launch gaps << grid.sync cost, measured R9) ----------------
__global__ void hist_kernel(const int* __restrict__ ei, int* __restrict__ deg) {
    int e = blockIdx.x * blockDim.x + threadIdx.x;
    if (e >= NUM_E) return;
    atomicAdd(&deg[ei[NUM_E + e]], 1);
}

__global__ void scan_local_kernel(const int* __restrict__ deg, int* __restrict__ rowptr,
                                  int* __restrict__ bsum) {
    __shared__ int ws[4];
    int b = blockIdx.x, t = threadIdx.x;
    int i = b * 256 + t;
    int lane = t & 63, wv = t >> 6;
    int v = (i < N_NODES) ? deg[i] : 0;
    int incl = v;
#pragma unroll
    for (int off = 1; off < 64; off <<= 1) {
        int u = __shfl_up(incl, off, 64);
        if (lane >= off) incl += u;
    }
    if (lane == 63) ws[wv] = incl;
    __syncthreads();
    if (t == 0) {
        int s = 0;
#pragma unroll
        for (int k = 0; k < 4; ++k) { int x = ws[k]; ws[k] = s; s += x; }
        bsum[b] = s;
    }
    __syncthreads();
    if (i < N_NODES) rowptr[i + 1] = ws[wv] + incl;
}

__global__ void scan_sums_kernel(int* __restrict__ bsum, int nb) {
    __shared__ int ws[4];
    int t = threadIdx.x;
    int lane = t & 63, wv = t >> 6;
    int v = (t < nb) ? bsum[t] : 0;
    int incl = v;
#pragma unroll
    for (int off = 1; off < 64; off <<= 1) {
        int u = __shfl_up(incl, off, 64);
        if (lane >= off) incl += u;
    }
    if (lane == 63) ws[wv] = incl;
    __syncthreads();
    if (t == 0) {
        int s = 0;
#pragma unroll
        for (int k = 0; k < 4; ++k) { int x = ws[k]; ws[k] = s; s += x; }
    }
    __syncthreads();
    if (t < nb) bsum[t] = ws[wv] + incl - v;   // exclusive
}

__global__ void scan_add_kernel(int* __restrict__ rowptr, const int* __restrict__ bsum) {
    int b = blockIdx.x, t = threadIdx.x;
    int i = b * 256 + t;
    if (i < N_NODES) rowptr[i + 1] += bsum[b];
    if (b == 0 && t == 0) rowptr[0] = 0;
}

__global__ void scatter_kernel(const int* __restrict__ ei, const int* __restrict__ rowptr,
                               int* __restrict__ fill, int* __restrict__ srcs) {
    int e = blockIdx.x * blockDim.x + threadIdx.x;
    if (e >= NUM_E) return;
    int dst = ei[NUM_E + e];
    int pos = rowptr[dst] + atomicAdd(&fill[dst], 1);
    srcs[pos] = ei[e];
}

__global__ void batch_offsets_kernel(const int* __restrict__ batch, int* __restrict__ goff) {
    int g = threadIdx.x;
    if (g > NUM_GRAPHS) return;
    int lo = 0, hi = N_NODES;
    while (lo < hi) {
        int mid = (lo + hi) >> 1;
        if (batch[mid] < g) lo = mid + 1; else hi = mid;
    }
    goff[g] = lo;
}

// ---------------- prep: W transpose->bf16 AND x->bf16 in one dispatch ----------------
__global__ void prep_all_kernel(const float* __restrict__ W1, const float* __restrict__ W2,
                                const float* __restrict__ W3, const float* __restrict__ x,
                                ushort_t* __restrict__ w1t, ushort_t* __restrict__ w2t,
                                ushort_t* __restrict__ w3t, ushort_t* __restrict__ xbf) {
    const int S1 = 128 * 256, S2 = 256 * 256, S3 = 256 * 64;
    const int SW = S1 + S2 + S3;                 // 81920
    const int SX = N_NODES * 128 / 4;            // 1.6M float4 units
    int i = blockIdx.x * blockDim.x + threadIdx.x;
    if (i < SX) {
        float4 v = ((const float4*)x)[i];
        ((uint2*)xbf)[i] = make_uint2(pkbf(v.x, v.y), pkbf(v.z, v.w));
    } else if (i < SX + SW) {
        int j = i - SX;
        if (j < S1) {
            int k = j / 256, n = j % 256;
            w1t[n * 128 + k] = f2bf(W1[j]);
        } else if (j < S1 + S2) {
            int jj = j - S1; int k = jj / 256, n = jj % 256;
            w2t[n * 256 + k] = f2bf(W2[jj]);
        } else {
            int jj = j - S1 - S2; int k = jj / 64, n = jj % 64;
            w3t[n * 256 + k] = f2bf(W3[jj]);
        }
    }
}

// ---------------- fused GEMM: BN-affine(A bf16)->bf16 @ Bt^T -> h(bf16) + per-head logits ----------------
// LDS UNION: As/Bs (K-loop) share storage with Cs (epilogue). Cs is only touched after the
// final K-loop __syncthreads (all As/Bs LDS reads complete), and Cs accesses are same-wave RAW.
// Cuts LDS 38.9 KB -> 22.5-23.5 KB => 4 -> 6-7 blocks/CU => more waves to overlap the barrier drain.
template<int K, int NFULL, int BN>
__global__ __launch_bounds__(256) void gemm_fused_kernel(const ushort_t* __restrict__ A,
                                                         const ushort_t* __restrict__ Bt,
                                                         ushort_t* __restrict__ C,
                                                         const float* __restrict__ stats,
                                                         const float* __restrict__ g,
                                                         const float* __restrict__ be,
                                                         const float* __restrict__ a_src,
                                                         const float* __restrict__ a_dst,
                                                         float* __restrict__ as_,
                                                         float* __restrict__ ad_) {
    const int NT = BN / 16;
    const int NG = BN / 64;
    constexpr int LOOP_BYTES = (128 * 40 + BN * 40) * 2;
    constexpr int EPI_BYTES  = 4 * 32 * 64 * 2;
    constexpr int SMEM_BYTES = LOOP_BYTES > EPI_BYTES ? LOOP_BYTES : EPI_BYTES;
    __shared__ __align__(16) unsigned char smem[SMEM_BYTES];
    ushort_t (*As)[40]     = (ushort_t (*)[40])smem;                       // [128][40]
    ushort_t (*Bs)[40]     = (ushort_t (*)[40])(smem + 128 * 40 * 2);      // [BN][40]
    ushort_t (*Cs)[32][64] = (ushort_t (*)[32][64])smem;                   // [4][32][64] (aliases As/Bs)
    __shared__ __align__(16) float aff_a[K], aff_b[K];
    __shared__ float asrc_s[BN], adst_s[BN];
    int tid = threadIdx.x;
    int lane = tid & 63, w = tid >> 6;
    int row0 = blockIdx.x * 128, col0 = blockIdx.y * BN;
    int m_l = lane & 15, q = lane >> 4;

    for (int c = tid; c < K; c += 256) {
        float a = 1.f, b = 0.f;
        if (stats) {
            float m = stats[c] * (1.f / N_NODES);
            float var = fmaxf(stats[256 + c] * (1.f / N_NODES) - m * m, 0.f);
            float rs = rsqrtf(var + EPS_BN) * g[c];
            a = rs; b = be[c] - m * rs;
        }
        aff_a[c] = a; aff_b[c] = b;
    }
    if (tid < BN) {
        asrc_s[tid] = a_src[col0 + tid];
        adst_s[tid] = a_dst[col0 + tid];
    }
    __syncthreads();

    f32x4 acc[2][NT];
#pragma unroll
    for (int r = 0; r < 2; ++r)
#pragma unroll
        for (int c = 0; c < NT; ++c) acc[r][c] = (f32x4){0.f, 0.f, 0.f, 0.f};

    int ar = tid >> 1, ako = (tid & 1) * 16;

    for (int k0 = 0; k0 < K; k0 += 32) {
        uint_t ow[8];
        int gr = row0 + ar;
        uint4 u0 = make_uint4(0, 0, 0, 0), u1 = make_uint4(0, 0, 0, 0);
        if (gr < N_NODES) {
            const ushort_t* ap = A + (long)gr * K + k0 + ako;
            u0 = *(const uint4*)ap;
            u1 = *(const uint4*)(ap + 8);
        }
        uint_t uu[8] = {u0.x, u0.y, u0.z, u0.w, u1.x, u1.y, u1.z, u1.w};
#pragma unroll
        for (int t = 0; t < 8; ++t) {
            int k = k0 + ako + t * 2;
            float lo = bflo(uu[t]) * aff_a[k] + aff_b[k];
            float hi = bfhi(uu[t]) * aff_a[k + 1] + aff_b[k + 1];
            ow[t] = pkbf(lo, hi);
        }
        if constexpr (BN == 128) {
            int br = tid >> 1, bko = (tid & 1) * 16;
            const ushort_t* bp = Bt + (long)(col0 + br) * K + k0 + bko;
            uint4 b0 = *(const uint4*)bp;
            uint4 b1 = *(const uint4*)(bp + 8);
            *(uint4*)&As[ar][ako] = make_uint4(ow[0], ow[1], ow[2], ow[3]);
            *(uint4*)&As[ar][ako + 8] = make_uint4(ow[4], ow[5], ow[6], ow[7]);
            *(uint4*)&Bs[br][bko] = b0;
            *(uint4*)&Bs[br][bko + 8] = b1;
        } else {
            int br = tid >> 2, bko = (tid & 3) * 8;
            uint4 bv = *(const uint4*)(Bt + (long)(col0 + br) * K + k0 + bko);
            *(uint4*)&As[ar][ako] = make_uint4(ow[0], ow[1], ow[2], ow[3]);
            *(uint4*)&As[ar][ako + 8] = make_uint4(ow[4], ow[5], ow[6], ow[7]);
            *(uint4*)&Bs[br][bko] = bv;
        }
        __syncthreads();

        bf16x8 af[2];
#pragma unroll
        for (int r = 0; r < 2; ++r)
            af[r] = *(const bf16x8*)&As[w * 32 + r * 16 + m_l][q * 8];
#pragma unroll
        for (int c = 0; c < NT; ++c) {
            bf16x8 bf = *(const bf16x8*)&Bs[c * 16 + m_l][q * 8];
#pragma unroll
            for (int r = 0; r < 2; ++r)
                acc[r][c] = __builtin_amdgcn_mfma_f32_16x16x32_bf16(af[r], bf, acc[r][c], 0, 0, 0);
        }
        __syncthreads();   // after this barrier As/Bs are dead -> Cs may alias
    }

    const int H = NFULL / 64;
#pragma unroll
    for (int gblk = 0; gblk < NG; ++gblk) {
        int hidx = blockIdx.y * NG + gblk;
        int colg = col0 + gblk * 64;
#pragma unroll
        for (int r = 0; r < 2; ++r)
#pragma unroll
            for (int cc = 0; cc < 4; ++cc)
#pragma unroll
                for (int i = 0; i < 4; ++i)
                    Cs[w][r * 16 + q * 4 + i][cc * 16 + m_l] = f2bf(acc[r][gblk * 4 + cc][i]);
        // same-wave LDS RAW: in-order DS pipe, no barrier needed
#pragma unroll
        for (int j = 0; j < 4; ++j) {
            int flat = j * 64 + lane;
            int lr = flat >> 3, chg = flat & 7;
            int gr = row0 + w * 32 + lr;
            uint4 u = *(uint4*)&Cs[w][lr][chg * 8];
            float f0 = bflo(u.x), f1 = bfhi(u.x), f2 = bflo(u.y), f3 = bfhi(u.y);
            float f4 = bflo(u.z), f5 = bfhi(u.z), f6 = bflo(u.w), f7 = bfhi(u.w);
            int cb = gblk * 64 + chg * 8;
            float s1 = f0 * asrc_s[cb] + f1 * asrc_s[cb + 1] + f2 * asrc_s[cb + 2] + f3 * asrc_s[cb + 3]
                     + f4 * asrc_s[cb + 4] + f5 * asrc_s[cb + 5] + f6 * asrc_s[cb + 6] + f7 * asrc_s[cb + 7];
            float s2 = f0 * adst_s[cb] + f1 * adst_s[cb + 1] + f2 * adst_s[cb + 2] + f3 * adst_s[cb + 3]
                     + f4 * adst_s[cb + 4] + f5 * adst_s[cb + 5] + f6 * adst_s[cb + 6] + f7 * adst_s[cb + 7];
#pragma unroll
            for (int o = 1; o < 8; o <<= 1) {
                s1 += __shfl_xor(s1, o, 64);
                s2 += __shfl_xor(s2, o, 64);
            }
            if (gr < N_NODES) {
                *(uint4*)(C + (long)gr * NFULL + colg + chg * 8) = u;
                if ((lane & 7) == 0) {
                    as_[gr * H + hidx] = s1;
                    ad_[gr * H + hidx] = s2;
                }
            }
        }
    }
}

// ---------------- GAT aggregation H=4: quarter-wave (16 lanes) per dst, 16 dst/block ----------------
__global__ __launch_bounds__(256) void agg4_kernel(const ushort_t* __restrict__ h,
                                                   const float* __restrict__ as_,
                                                   const float* __restrict__ ad_,
                                                   const int* __restrict__ rowptr,
                                                   const int* __restrict__ srcs,
                                                   const float* __restrict__ bias,
                                                   ushort_t* __restrict__ out) {
    __shared__ float alds[4][256];
    int lane = threadIdx.x & 63, w = threadIdx.x >> 6;
    int q = lane >> 4, cl = lane & 15;
    int n = blockIdx.x * 16 + w * 4 + q;
    if (n >= N_NODES) return;
    int start = rowptr[n];
    int deg = rowptr[n + 1] - start;

    float4 adv = *(const float4*)(ad_ + n * 4);
    float ad4[4] = {adv.x, adv.y, adv.z, adv.w};

    float mx[4] = {-1e30f, -1e30f, -1e30f, -1e30f};
    float dn[4] = {0.f, 0.f, 0.f, 0.f};
    int s0reg = 0;
    {
        float vst[4] = {-1e30f, -1e30f, -1e30f, -1e30f};
        if (deg > 0) s0reg = srcs[start + min(cl, deg - 1)];
        if (cl < deg) {
            float4 av = *(const float4*)(as_ + s0reg * 4);
            float vv[4] = {av.x + ad4[0], av.y + ad4[1], av.z + ad4[2], av.w + ad4[3]};
#pragma unroll
            for (int hh = 0; hh < 4; ++hh) {
                float v = vv[hh] > 0.f ? vv[hh] : 0.2f * vv[hh];
                vst[hh] = v; mx[hh] = v; dn[hh] = 1.f;
            }
        }
        *(float4*)&alds[w][lane * 4] = make_float4(vst[0], vst[1], vst[2], vst[3]);
        for (int j = cl + 16; j < deg; j += 16) {
            int s = srcs[start + j];
            float4 av = *(const float4*)(as_ + s * 4);
            float vv[4] = {av.x + ad4[0], av.y + ad4[1], av.z + ad4[2], av.w + ad4[3]};
#pragma unroll
            for (int hh = 0; hh < 4; ++hh) {
                float v = vv[hh] > 0.f ? vv[hh] : 0.2f * vv[hh];
                float mn = fmaxf(mx[hh], v);
                dn[hh] = dn[hh] * __expf(mx[hh] - mn) + __expf(v - mn);
                mx[hh] = mn;
            }
        }
    }
    float mloc[4] = {mx[0], mx[1], mx[2], mx[3]};
#pragma unroll
    for (int off = 1; off < 16; off <<= 1)
#pragma unroll
        for (int hh = 0; hh < 4; ++hh) mx[hh] = fmaxf(mx[hh], __shfl_xor(mx[hh], off, 64));
#pragma unroll
    for (int hh = 0; hh < 4; ++hh) dn[hh] *= __expf(mloc[hh] - mx[hh]);
#pragma unroll
    for (int off = 1; off < 16; off <<= 1)
#pragma unroll
        for (int hh = 0; hh < 4; ++hh) dn[hh] += __shfl_xor(dn[hh], off, 64);
    float inv[4];
#pragma unroll
    for (int hh = 0; hh < 4; ++hh) inv[hh] = dn[hh] > 0.f ? 1.f / dn[hh] : 0.f;

    {
        float4 vv = *(const float4*)&alds[w][lane * 4];
        float4 al;
        al.x = __expf(vv.x - mx[0]) * inv[0];
        al.y = __expf(vv.y - mx[1]) * inv[1];
        al.z = __expf(vv.z - mx[2]) * inv[2];
        al.w = __expf(vv.w - mx[3]) * inv[3];
        *(float4*)&alds[w][lane * 4] = al;
    }

    int hd = cl >> 2;
    float acc[16];
#pragma unroll
    for (int k = 0; k < 16; ++k) acc[k] = 0.f;
    for (int chunk = 0; chunk < deg || chunk == 0; chunk += 16) {
        int s = s0reg;
        if (chunk > 0) {
            int j = chunk + cl;
            float4 al = make_float4(0.f, 0.f, 0.f, 0.f);
            s = srcs[start + min(j, deg - 1)];
            if (j < deg) {
                float4 av = *(const float4*)(as_ + s * 4);
                float vv[4] = {av.x + ad4[0], av.y + ad4[1], av.z + ad4[2], av.w + ad4[3]};
                float a4[4];
#pragma unroll
                for (int hh = 0; hh < 4; ++hh) {
                    float v = vv[hh] > 0.f ? vv[hh] : 0.2f * vv[hh];
                    a4[hh] = __expf(v - mx[hh]) * inv[hh];
                }
                al = make_float4(a4[0], a4[1], a4[2], a4[3]);
            }
            *(float4*)&alds[w][lane * 4] = al;
        }
        int cnt = min(16, deg - chunk);
        if (cnt < 0) cnt = 0;
#pragma unroll 4
        for (int e = 0; e < cnt; ++e) {
            int se = __shfl(s, q * 16 + e, 64);
            float al = alds[w][(q * 16 + e) * 4 + hd];
            const ushort_t* hr = h + (long)se * 256 + cl * 16;
            uint4 u0 = *(const uint4*)hr;
            uint4 u1 = *(const uint4*)(hr + 8);
            acc[0] += al * bflo(u0.x);  acc[1] += al * bfhi(u0.x);
            acc[2] += al * bflo(u0.y);  acc[3] += al * bfhi(u0.y);
            acc[4] += al * bflo(u0.z);  acc[5] += al * bfhi(u0.z);
            acc[6] += al * bflo(u0.w);  acc[7] += al * bfhi(u0.w);
            acc[8] += al * bflo(u1.x);  acc[9] += al * bfhi(u1.x);
            acc[10] += al * bflo(u1.y); acc[11] += al * bfhi(u1.y);
            acc[12] += al * bflo(u1.z); acc[13] += al * bfhi(u1.z);
            acc[14] += al * bflo(u1.w); acc[15] += al * bfhi(u1.w);
        }
        if (deg <= 16) break;
    }
    int c0 = cl * 16;
    uint_t ow[8];
#pragma unroll
    for (int t = 0; t < 8; ++t) {
        float lo = fmaxf(acc[t * 2] + bias[c0 + t * 2], 0.f);
        float hi = fmaxf(acc[t * 2 + 1] + bias[c0 + t * 2 + 1], 0.f);
        ow[t] = pkbf(lo, hi);
    }
    ushort_t* op = out + (long)n * 256 + c0;
    *(uint4*)op = make_uint4(ow[0], ow[1], ow[2], ow[3]);
    *(uint4*)(op + 8) = make_uint4(ow[4], ow[5], ow[6], ow[7]);
}

// ---------------- GAT aggregation H=1: octant (8 lanes) per dst, 32 dst/block ----------------
__global__ __launch_bounds__(256) void agg1_kernel(const ushort_t* __restrict__ h,
                                                   const float* __restrict__ as_,
                                                   const float* __restrict__ ad_,
                                                   const int* __restrict__ rowptr,
                                                   const int* __restrict__ srcs,
                                                   const float* __restrict__ bias,
                                                   ushort_t* __restrict__ out) {
    __shared__ float alds1[4][64];
    int lane = threadIdx.x & 63, w = threadIdx.x >> 6;
    int o = lane >> 3, cl = lane & 7;
    int n = blockIdx.x * 32 + w * 8 + o;
    if (n >= N_NODES) return;
    int start = rowptr[n];
    int deg = rowptr[n + 1] - start;
    float adn = ad_[n];

    float mx = -1e30f, dn = 0.f;
    int s0reg = 0;
    {
        float vst = -1e30f;
        if (deg > 0) s0reg = srcs[start + min(cl, deg - 1)];
        if (cl < deg) {
            float v = as_[s0reg] + adn;
            v = v > 0.f ? v : 0.2f * v;
            vst = v; mx = v; dn = 1.f;
        }
        alds1[w][lane] = vst;
        for (int j = cl + 8; j < deg; j += 8) {
            int s = srcs[start + j];
            float v = as_[s] + adn;
            v = v > 0.f ? v : 0.2f * v;
            float mn = fmaxf(mx, v);
            dn = dn * __expf(mx - mn) + __expf(v - mn);
            mx = mn;
        }
    }
    float mloc = mx;
#pragma unroll
    for (int off = 1; off < 8; off <<= 1) mx = fmaxf(mx, __shfl_xor(mx, off, 64));
    dn *= __expf(mloc - mx);
#pragma unroll
    for (int off = 1; off < 8; off <<= 1) dn += __shfl_xor(dn, off, 64);
    float inv = dn > 0.f ? 1.f / dn : 0.f;

    alds1[w][lane] = __expf(alds1[w][lane] - mx) * inv;

    float acc[8] = {0.f, 0.f, 0.f, 0.f, 0.f, 0.f, 0.f, 0.f};
    for (int chunk = 0; chunk < deg || chunk == 0; chunk += 8) {
        int s = s0reg;
        if (chunk > 0) {
            int j = chunk + cl;
            float al = 0.f;
            s = srcs[start + min(j, deg - 1)];
            if (j < deg) {
                float v = as_[s] + adn;
                v = v > 0.f ? v : 0.2f * v;
                al = __expf(v - mx) * inv;
            }
            alds1[w][lane] = al;
        }
        int cnt = min(8, deg - chunk);
        if (cnt < 0) cnt = 0;
#pragma unroll 4
        for (int e = 0; e < cnt; ++e) {
            int se = __shfl(s, o * 8 + e, 64);
            float al = alds1[w][o * 8 + e];
            const ushort_t* hr = h + (long)se * 64 + cl * 8;
            uint4 u = *(const uint4*)hr;
            acc[0] += al * bflo(u.x); acc[1] += al * bfhi(u.x);
            acc[2] += al * bflo(u.y); acc[3] += al * bfhi(u.y);
            acc[4] += al * bflo(u.z); acc[5] += al * bfhi(u.z);
            acc[6] += al * bflo(u.w); acc[7] += al * bfhi(u.w);
        }
        if (deg <= 8) break;
    }
    int c0 = cl * 8;
    uint_t ow[4];
#pragma unroll
    for (int t = 0; t < 4; ++t) {
        float lo = fmaxf(acc[t * 2] + bias[c0 + t * 2], 0.f);
        float hi = fmaxf(acc[t * 2 + 1] + bias[c0 + t * 2 + 1], 0.f);
        ow[t] = pkbf(lo, hi);
    }
    *(uint4*)(out + (long)n * 64 + c0) = make_uint4(ow[0], ow[1], ow[2], ow[3]);
}

// ---------------- BatchNorm stats on bf16, coalesced ----------------
template<int C>
__global__ __launch_bounds__(256) void bn_stats_bf16(const ushort_t* __restrict__ x,
                                                     float* __restrict__ stats) {
    const int GROUPS = C / 8;
    const int RS = 256 / GROUPS;
    int tid = threadIdx.x;
    int cg_ = tid % GROUPS;
    int rs = tid / GROUPS;
    float s[8], s2[8];
#pragma unroll
    for (int k = 0; k < 8; ++k) { s[k] = 0.f; s2[k] = 0.f; }
    for (int n = blockIdx.x * RS + rs; n < N_NODES; n += gridDim.x * RS) {
        uint4 u = *(const uint4*)(x + (long)n * C + cg_ * 8);
        float f[8] = {bflo(u.x), bfhi(u.x), bflo(u.y), bfhi(u.y),
                      bflo(u.z), bfhi(u.z), bflo(u.w), bfhi(u.w)};
#pragma unroll
        for (int k = 0; k < 8; ++k) { s[k] += f[k]; s2[k] += f[k] * f[k]; }
    }
    __shared__ float red[256][16];
#pragma unroll
    for (int k = 0; k < 8; ++k) { red[tid][k] = s[k]; red[tid][8 + k] = s2[k]; }
    __syncthreads();
    if (tid < C) {
        int g = tid >> 3, k = tid & 7;
        float a = 0.f, b = 0.f;
        for (int r = 0; r < RS; ++r) {
            a += red[g + r * GROUPS][k];
            b += red[g + r * GROUPS][8 + k];
        }
        atomicAdd(&stats[tid], a);
        atomicAdd(&stats[256 + tid], b);
    }
}

// ---------------- pool (BN affine fused) + FC, one block per graph ----------------
__global__ __launch_bounds__(256) void pool_fc_kernel(const ushort_t* __restrict__ h,
                                                      const int* __restrict__ goff,
                                                      const float* __restrict__ stats,
                                                      const float* __restrict__ g3,
                                                      const float* __restrict__ be3,
                                                      const float* __restrict__ fcW,
                                                      const float* __restrict__ fcb,
                                                      float* __restrict__ out) {
    int g = blockIdx.x;
    int c = threadIdx.x & 63;
    int ty = threadIdx.x >> 6;
    int s = goff[g], e = goff[g + 1];
    float sum = 0.f;
    for (int n = s + ty; n < e; n += 4) sum += bflo((uint_t)h[(long)n * 64 + c]);
    __shared__ float red[4][64];
    __shared__ float pv[64];
    red[ty][c] = sum;
    __syncthreads();
    if (ty == 0) {
        float tot = red[0][c] + red[1][c] + red[2][c] + red[3][c];
        float v = tot / fmaxf((float)(e - s), 1.f);
        float m = stats[c] * (1.f / N_NODES);
        float var = fmaxf(stats[256 + c] * (1.f / N_NODES) - m * m, 0.f);
        pv[c] = (v - m) * rsqrtf(var + EPS_BN) * g3[c] + be3[c];
    }
    __syncthreads();
    if (threadIdx.x < 10) {
        int j = threadIdx.x;
        float acc = fcb[j];
#pragma unroll
        for (int k = 0; k < 64; ++k) acc += pv[k] * fcW[k * 10 + j];
        out[g * 10 + j] = acc;
    }
}

extern "C" void kernel_launch(void* const* d_in, const int* in_sizes, int n_in,
                              void* d_out, int out_size, void* d_ws, size_t ws_size,
                              hipStream_t stream) {
    const float* x      = (const float*)d_in[0];
    const int*   ei     = (const int*)d_in[1];
    const int*   batch  = (const int*)d_in[2];
    const float* W1     = (const float*)d_in[3];
    const float* a_src1 = (const float*)d_in[4];
    const float* a_dst1 = (const float*)d_in[5];
    const float* b1     = (const float*)d_in[6];
    const float* g1     = (const float*)d_in[7];
    const float* be1    = (const float*)d_in[8];
    const float* W2     = (const float*)d_in[9];
    const float* a_src2 = (const float*)d_in[10];
    const float* a_dst2 = (const float*)d_in[11];
    const float* b2     = (const float*)d_in[12];
    const float* g2     = (const float*)d_in[13];
    const float* be2    = (const float*)d_in[14];
    const float* W3     = (const float*)d_in[15];
    const float* a_src3 = (const float*)d_in[16];
    const float* a_dst3 = (const float*)d_in[17];
    const float* b3     = (const float*)d_in[18];
    const float* g3     = (const float*)d_in[19];
    const float* be3    = (const float*)d_in[20];
    const float* fcW    = (const float*)d_in[21];
    const float* fcb    = (const float*)d_in[22];
    float* out = (float*)d_out;

    const size_t N = N_NODES, E = NUM_E;
    ushort_t* hbf    = (ushort_t*)d_ws;                 // [N,256] bf16 GEMM output
    ushort_t* hagg   = hbf + N * 256;                   // [N,256] bf16 agg output (pre-BN)
    ushort_t* xbf    = hagg + N * 256;                  // [N,128] bf16 x
    ushort_t* w1t    = xbf + N * 128;                   // [256][128]
    ushort_t* w2t    = w1t + 256 * 128;                 // [256][256]
    ushort_t* w3t    = w2t + 256 * 256;                 // [64][256]
    float*    as_    = (float*)(w3t + 64 * 256 + 128);  // [N,4]
    float*    ad_    = as_ + N * 4;                     // [N,4]
    int*      deg    = (int*)(ad_ + N * 4);             // [N]   (zero region start)
    int*      fill   = deg + N;                         // [N]
    float*    statsA = (float*)(fill + N);              // [512]
    float*    statsB = statsA + 512;                    // [512]
    float*    statsC = statsB + 512;                    // [512]
    int*      rowptr = (int*)(statsC + 512);            // [N+1]
    int*      srcs   = rowptr + (N + 1);                // [E]
    int*      bsum   = srcs + E;                        // [256]
    int*      goff   = bsum + 256;                      // [65]

    const int NB = (N_NODES + 255) / 256;  // 196

    // ---- setup: split chain (measured R9: grid.sync cooperative fusion = 5-10x slower) ----
    hipMemsetAsync(deg, 0, sizeof(int) * (2 * N + 3 * 512), stream);
    hist_kernel<<<(NUM_E + 255) / 256, 256, 0, stream>>>(ei, deg);
    scan_local_kernel<<<NB, 256, 0, stream>>>(deg, rowptr, bsum);
    scan_sums_kernel<<<1, 256, 0, stream>>>(bsum, NB);
    scan_add_kernel<<<NB, 256, 0, stream>>>(rowptr, bsum);
    scatter_kernel<<<(NUM_E + 255) / 256, 256, 0, stream>>>(ei, rowptr, fill, srcs);
    batch_offsets_kernel<<<1, 128, 0, stream>>>(batch, goff);
    prep_all_kernel<<<(N_NODES * 128 / 4 + 128 * 256 + 256 * 256 + 256 * 64 + 255) / 256, 256, 0, stream>>>(
        W1, W2, W3, x, w1t, w2t, w3t, xbf);

    const int GB = (N_NODES + 127) / 128;  // 391

    // ---- layer 1: A = xbf (identity affine), BN=128 (2 heads/block) ----
    gemm_fused_kernel<128, 256, 128><<<dim3(GB, 2), 256, 0, stream>>>(
        xbf, w1t, hbf, nullptr, nullptr, nullptr, a_src1, a_dst1, as_, ad_);
    agg4_kernel<<<(N_NODES + 15) / 16, 256, 0, stream>>>(hbf, as_, ad_, rowptr, srcs, b1, hagg);
    bn_stats_bf16<256><<<128, 256, 0, stream>>>(hagg, statsA);

    // ---- layer 2 ----
    gemm_fused_kernel<256, 256, 128><<<dim3(GB, 2), 256, 0, stream>>>(
        hagg, w2t, hbf, statsA, g1, be1, a_src2, a_dst2, as_, ad_);
    agg4_kernel<<<(N_NODES + 15) / 16, 256, 0, stream>>>(hbf, as_, ad_, rowptr, srcs, b2, hagg);
    bn_stats_bf16<256><<<128, 256, 0, stream>>>(hagg, statsB);

    // ---- layer 3 ----
    gemm_fused_kernel<256, 64, 64><<<dim3(GB, 1), 256, 0, stream>>>(
        hagg, w3t, hbf, statsB, g2, be2, a_src3, a_dst3, as_, ad_);
    agg1_kernel<<<(N_NODES + 31) / 32, 256, 0, stream>>>(hbf, as_, ad_, rowptr, srcs, b3, hagg);
    bn_stats_bf16<64><<<128, 256, 0, stream>>>(hagg, statsC);

    // ---- pool + BN3 affine + FC in one ----
    pool_fc_kernel<<<NUM_GRAPHS, 256, 0, stream>>>(hagg, goff, statsC, g3, be3, fcW, fcb, out);
}